// Round 12
// baseline (437.746 us; speedup 1.0000x reference)
//
#include <hip/hip_runtime.h>

#define NODES 50000
#define FIN   256
#define FOUT  128
#define EPS   1e-5f
#define SLOPE 0.1f
#define SCAN_CHUNK 512
#define SCAN_NB ((NODES + SCAN_CHUNK - 1) / SCAN_CHUNK)  // 98
#define AGG_NB 2048

typedef __attribute__((ext_vector_type(8))) short short8_t;   // 8 bf16 = 4 VGPRs
typedef __attribute__((ext_vector_type(4))) float f32x4_t;    // MFMA accumulator

// fp32 -> bf16 bits, round-to-nearest-even
__device__ __forceinline__ ushort f2bf(float f) {
    union { float f; unsigned u; } v; v.f = f;
    return (ushort)((v.u + 0x7FFFu + ((v.u >> 16) & 1u)) >> 16);
}
// bf16 bits -> fp32
__device__ __forceinline__ float bf2f(ushort u) {
    union { unsigned x; float f; } v; v.x = ((unsigned)u) << 16; return v.f;
}

// ---------------------------------------------------------------- degree count
__global__ void deg_kernel(const int* __restrict__ col, int E, int* __restrict__ deg) {
    int e = blockIdx.x * 256 + threadIdx.x;
    if (e < E) atomicAdd(&deg[col[e]], 1);
}

// ------------------------------------------------- hierarchical scan, pass 1
__global__ __launch_bounds__(256) void scan1_kernel(const int* __restrict__ deg,
                                                    int* __restrict__ partials, int Nn) {
    const int t = threadIdx.x;
    const int i0 = blockIdx.x * SCAN_CHUNK + 2 * t;
    int e0 = (i0 < Nn) ? deg[i0] : 0;
    int e1 = (i0 + 1 < Nn) ? deg[i0 + 1] : 0;
    __shared__ int sh[256];
    sh[t] = e0 + e1;
    __syncthreads();
    for (int off = 128; off > 0; off >>= 1) {
        if (t < off) sh[t] += sh[t + off];
        __syncthreads();
    }
    if (t == 0) partials[blockIdx.x] = sh[0];
}

// ------------------------------------------------- pass 2: scan partials
__global__ __launch_bounds__(128) void scan2_kernel(const int* __restrict__ partials,
                                                    int* __restrict__ partials_pre,
                                                    int* __restrict__ offN, int total) {
    __shared__ int sh[128];
    const int t = threadIdx.x;
    int v = (t < SCAN_NB) ? partials[t] : 0;
    sh[t] = v;
    __syncthreads();
    for (int off = 1; off < 128; off <<= 1) {
        int u = (t >= off) ? sh[t - off] : 0;
        __syncthreads();
        sh[t] += u;
        __syncthreads();
    }
    if (t < SCAN_NB) partials_pre[t] = sh[t] - v;
    if (t == 0) *offN = total;
}

// ------------------------------------------------- pass 3: in-block scan + prefix (+ fused dinv)
__global__ __launch_bounds__(256) void scan3_kernel(const int* __restrict__ deg,
                                                    const int* __restrict__ partials_pre,
                                                    int* __restrict__ offsets,
                                                    float* __restrict__ dinv, int Nn) {
    const int t = threadIdx.x;
    const int i0 = blockIdx.x * SCAN_CHUNK + 2 * t;
    int e0 = (i0 < Nn) ? deg[i0] : 0;
    int e1 = (i0 + 1 < Nn) ? deg[i0 + 1] : 0;
    int s = e0 + e1;
    __shared__ int sh[256];
    sh[t] = s;
    __syncthreads();
    for (int off = 1; off < 256; off <<= 1) {
        int u = (t >= off) ? sh[t - off] : 0;
        __syncthreads();
        sh[t] += u;
        __syncthreads();
    }
    int ex = sh[t] - s + partials_pre[blockIdx.x];
    if (i0 < Nn)     { offsets[i0] = ex;          dinv[i0] = rsqrtf((float)(e0 + 1)); }
    if (i0 + 1 < Nn) { offsets[i0 + 1] = ex + e0; dinv[i0 + 1] = rsqrtf((float)(e1 + 1)); }
}

// ---------------------------------------------------------------- CSR fill
__global__ void fill_kernel(const int* __restrict__ row, const int* __restrict__ col, int E,
                            const int* __restrict__ offsets, int* __restrict__ cursor,
                            int* __restrict__ srcs) {
    int e = blockIdx.x * 256 + threadIdx.x;
    if (e < E) {
        int c = col[e];
        int p = offsets[c] + atomicAdd(&cursor[c], 1);
        srcs[p] = row[e];
    }
}

// ---------------------------------------------------------------- W -> bf16 transposed
template <int K>
__global__ __launch_bounds__(256) void wcvt_kernel(const float* __restrict__ W,
                                                   ushort* __restrict__ Bt) {
    int idx = blockIdx.x * 256 + threadIdx.x;
    int k = idx >> 7, n = idx & 127;
    if (k < K) Bt[n * K + k] = f2bf(W[idx]);
}

// ---------------------------------------------------------------- BN partial-sum reduce -> scale/shift
// ps1/ps2: [AGG_NB][128] per-block partial sum / sumsq from agg_kernel.
__global__ __launch_bounds__(1024) void bn_reduce_kernel(const float* __restrict__ ps1,
                                                         const float* __restrict__ ps2,
                                                         const float* __restrict__ gamma,
                                                         const float* __restrict__ beta,
                                                         float* __restrict__ scale,
                                                         float* __restrict__ shift) {
    const int f = threadIdx.x & 127;
    const int c = threadIdx.x >> 7;  // 0..7
    float s1 = 0.f, s2 = 0.f;
    for (int b = c; b < AGG_NB; b += 8) {
        s1 += ps1[b * 128 + f];
        s2 += ps2[b * 128 + f];
    }
    __shared__ float r1[8][128], r2[8][128];
    r1[c][f] = s1;
    r2[c][f] = s2;
    __syncthreads();
    if (threadIdx.x < 128) {
        float t1 = 0.f, t2 = 0.f;
#pragma unroll
        for (int k = 0; k < 8; ++k) { t1 += r1[k][f]; t2 += r2[k][f]; }
        const float invN = 1.0f / (float)NODES;
        float mu  = t1 * invN;
        float var = t2 * invN - mu * mu;
        float sc  = gamma[f] * rsqrtf(var + EPS);
        scale[f] = sc;
        shift[f] = beta[f] - mu * sc;
    }
}

// ---------------------------------------------------------------- bf16 MFMA GEMM + bias (+opt fused BN+LeakyReLU on A)
// C[M,128] (bf16) = act(A[M,K]) @ B[K,128] + bias, act = FUSE ? leakyrelu(A*scale+shift) : A.
// Bt = B^T bf16 [128][K]. BM=128, BN=128, BK=32; 4 waves x (2 m-tiles x 8 n-tiles) 16x16x32.
// Fragment mapping (HW-verified, guide §3 m89/m91):
//   A: lane l -> A[l&15][(l>>4)*8+j] ; B: lane l -> B[(l>>4)*8+j][l&15]
//   D: lane l, reg r -> C[(l>>4)*4+r][l&15]
template <int K, bool FUSE>
__global__ __launch_bounds__(256) void gemm_mfma_kernel(const float* __restrict__ A,
                                                        const ushort* __restrict__ Bt,
                                                        const float* __restrict__ bias,
                                                        const float* __restrict__ scale,
                                                        const float* __restrict__ shift,
                                                        ushort* __restrict__ C, int M) {
    __shared__ ushort As[128 * 40];  // [row][k] bf16, row stride 40 (pad)
    __shared__ ushort Bs[128 * 40];  // [n][k]   bf16, row stride 40 (pad)
    const int tid  = threadIdx.x;
    const int lane = tid & 63;
    const int w    = tid >> 6;
    const int m0   = blockIdx.x * 128;
    const int ml   = lane & 15;
    const int kg   = lane >> 4;

    f32x4_t acc[2][8];
    const f32x4_t zero = {0.f, 0.f, 0.f, 0.f};
#pragma unroll
    for (int a = 0; a < 2; ++a)
#pragma unroll
        for (int b = 0; b < 8; ++b) acc[a][b] = zero;

    const int sr = tid >> 1;
    const int sh = tid & 1;
    const bool aok = (m0 + sr) < M;
    const float* ap = A + (size_t)(m0 + sr) * K + sh * 16;

    for (int k0 = 0; k0 < K; k0 += 32) {
        __syncthreads();
        // ---- stage A tile [128][32] fp32 -> (BN+lrelu) -> bf16
        float vv[16];
        if (aok) {
            const float* p = ap + k0;
            *(float4*)&vv[0]  = *(const float4*)(p + 0);
            *(float4*)&vv[4]  = *(const float4*)(p + 4);
            *(float4*)&vv[8]  = *(const float4*)(p + 8);
            *(float4*)&vv[12] = *(const float4*)(p + 12);
            if (FUSE) {
                int kb = k0 + sh * 16;
#pragma unroll
                for (int j = 0; j < 16; ++j) {
                    float val = fmaf(vv[j], scale[kb + j], shift[kb + j]);
                    vv[j] = (val >= 0.f) ? val : SLOPE * val;
                }
            }
        } else {
#pragma unroll
            for (int j = 0; j < 16; ++j) vv[j] = 0.f;
        }
        short8_t oa, ob;
#pragma unroll
        for (int j = 0; j < 8; ++j) { oa[j] = (short)f2bf(vv[j]); ob[j] = (short)f2bf(vv[8 + j]); }
        *(short8_t*)&As[sr * 40 + sh * 16]     = oa;
        *(short8_t*)&As[sr * 40 + sh * 16 + 8] = ob;
        // ---- stage B tile [128][32]
#pragma unroll
        for (int cc = 0; cc < 2; ++cc) {
            int c  = tid + cc * 256;
            int bn = c >> 2;
            int bs = (c & 3) * 8;
            *(short8_t*)&Bs[bn * 40 + bs] = *(const short8_t*)&Bt[bn * K + k0 + bs];
        }
        __syncthreads();
        // ---- 16 MFMA
        short8_t af0 = *(const short8_t*)&As[(w * 32 + ml) * 40 + kg * 8];
        short8_t af1 = *(const short8_t*)&As[(w * 32 + 16 + ml) * 40 + kg * 8];
#pragma unroll
        for (int nt = 0; nt < 8; ++nt) {
            short8_t bf = *(const short8_t*)&Bs[(nt * 16 + ml) * 40 + kg * 8];
            acc[0][nt] = __builtin_amdgcn_mfma_f32_16x16x32_bf16(af0, bf, acc[0][nt], 0, 0, 0);
            acc[1][nt] = __builtin_amdgcn_mfma_f32_16x16x32_bf16(af1, bf, acc[1][nt], 0, 0, 0);
        }
    }
    // ---- epilogue: bias + store bf16
#pragma unroll
    for (int nt = 0; nt < 8; ++nt) {
        float bv = bias[nt * 16 + ml];
#pragma unroll
        for (int mt = 0; mt < 2; ++mt) {
            int mr0 = m0 + w * 32 + mt * 16 + kg * 4;
#pragma unroll
            for (int rr = 0; rr < 4; ++rr) {
                int mr = mr0 + rr;
                if (mr < M) C[(size_t)mr * FOUT + nt * 16 + ml] = f2bf(acc[mt][nt][rr] + bv);
            }
        }
    }
}

// ---------------------------------------------------------------- aggregation + fused BN stats
// out[i] = dinv[i]^2 * h[i] + sum_{s in N(i)} dinv[i]*dinv[s]*h[s]  (h bf16, out fp32)
// One node per 16-lane group (16 x ushort8 = 128 bf16 = 256B/row), 16 nodes/block,
// grid-stride over nodes. Per-thread register accumulation of per-feature
// sum/sumsq over its nodes, block LDS reduce, coalesced per-block partial write.
__global__ __launch_bounds__(256) void agg_kernel(const ushort* __restrict__ h,
                                                  const float* __restrict__ dinv,
                                                  const int* __restrict__ offsets,
                                                  const int* __restrict__ srcs,
                                                  float* __restrict__ out,
                                                  float* __restrict__ ps1,
                                                  float* __restrict__ ps2, int Nn) {
    const int tid  = threadIdx.x;
    const int g    = tid >> 4;   // 0..15 group
    const int lane = tid & 15;   // 0..15
    float s1[8], s2[8];
#pragma unroll
    for (int j = 0; j < 8; ++j) { s1[j] = 0.f; s2[j] = 0.f; }

    for (int node = blockIdx.x * 16 + g; node < Nn; node += AGG_NB * 16) {
        float di = dinv[node];
        short8_t hv = *(const short8_t*)&h[(size_t)node * 128 + lane * 8];
        float sw = di * di;
        float a0[8], a1[8];
#pragma unroll
        for (int j = 0; j < 8; ++j) { a0[j] = sw * bf2f((ushort)hv[j]); a1[j] = 0.f; }
        int beg = offsets[node], end = offsets[node + 1];
        int e = beg;
        for (; e + 4 <= end; e += 4) {
            int i0 = srcs[e], i1 = srcs[e + 1], i2 = srcs[e + 2], i3 = srcs[e + 3];
            float n0 = di * dinv[i0], n1 = di * dinv[i1];
            float n2 = di * dinv[i2], n3 = di * dinv[i3];
            short8_t v0 = *(const short8_t*)&h[(size_t)i0 * 128 + lane * 8];
            short8_t v1 = *(const short8_t*)&h[(size_t)i1 * 128 + lane * 8];
            short8_t v2 = *(const short8_t*)&h[(size_t)i2 * 128 + lane * 8];
            short8_t v3 = *(const short8_t*)&h[(size_t)i3 * 128 + lane * 8];
#pragma unroll
            for (int j = 0; j < 8; ++j) {
                a0[j] = fmaf(n0, bf2f((ushort)v0[j]), a0[j]);
                a1[j] = fmaf(n1, bf2f((ushort)v1[j]), a1[j]);
                a0[j] = fmaf(n2, bf2f((ushort)v2[j]), a0[j]);
                a1[j] = fmaf(n3, bf2f((ushort)v3[j]), a1[j]);
            }
        }
        for (; e < end; ++e) {
            int s = srcs[e];
            float n = di * dinv[s];
            short8_t v = *(const short8_t*)&h[(size_t)s * 128 + lane * 8];
#pragma unroll
            for (int j = 0; j < 8; ++j) a0[j] = fmaf(n, bf2f((ushort)v[j]), a0[j]);
        }
        float4 o0, o1;
        o0.x = a0[0] + a1[0]; o0.y = a0[1] + a1[1];
        o0.z = a0[2] + a1[2]; o0.w = a0[3] + a1[3];
        o1.x = a0[4] + a1[4]; o1.y = a0[5] + a1[5];
        o1.z = a0[6] + a1[6]; o1.w = a0[7] + a1[7];
        float* op = &out[(size_t)node * 128 + lane * 8];
        *(float4*)op       = o0;
        *(float4*)(op + 4) = o1;
        s1[0] += o0.x; s2[0] += o0.x * o0.x;  s1[1] += o0.y; s2[1] += o0.y * o0.y;
        s1[2] += o0.z; s2[2] += o0.z * o0.z;  s1[3] += o0.w; s2[3] += o0.w * o0.w;
        s1[4] += o1.x; s2[4] += o1.x * o1.x;  s1[5] += o1.y; s2[5] += o1.y * o1.y;
        s1[6] += o1.z; s2[6] += o1.z * o1.z;  s1[7] += o1.w; s2[7] += o1.w * o1.w;
    }

    // block reduce: feature f = lane*8 + j; sum over the 16 groups
    __shared__ float red[256][8];
#pragma unroll
    for (int j = 0; j < 8; ++j) red[tid][j] = s1[j];
    __syncthreads();
    if (tid < 128) {
        int ln = tid >> 3, jj = tid & 7;
        float s = 0.f;
#pragma unroll
        for (int gg = 0; gg < 16; ++gg) s += red[gg * 16 + ln][jj];
        ps1[blockIdx.x * 128 + tid] = s;
    }
    __syncthreads();
#pragma unroll
    for (int j = 0; j < 8; ++j) red[tid][j] = s2[j];
    __syncthreads();
    if (tid < 128) {
        int ln = tid >> 3, jj = tid & 7;
        float s = 0.f;
#pragma unroll
        for (int gg = 0; gg < 16; ++gg) s += red[gg * 16 + ln][jj];
        ps2[blockIdx.x * 128 + tid] = s;
    }
}

// ---------------------------------------------------------------- BN apply (scale/shift) + leaky relu
__global__ __launch_bounds__(256) void bn_apply_kernel(float* __restrict__ x,
                                                       const float* __restrict__ scale,
                                                       const float* __restrict__ shift, int Nn) {
    size_t i = (size_t)blockIdx.x * 256 + threadIdx.x;
    if (i >= (size_t)Nn * FOUT) return;
    int f = (int)(i & 127);
    float v = fmaf(x[i], scale[f], shift[f]);
    x[i] = (v >= 0.f) ? v : SLOPE * v;
}

// ================================================================ launch
extern "C" void kernel_launch(void* const* d_in, const int* in_sizes, int n_in,
                              void* d_out, int out_size, void* d_ws, size_t ws_size,
                              hipStream_t stream) {
    const float* x  = (const float*)d_in[0];
    const int*   ei = (const int*)d_in[1];
    const float* W1 = (const float*)d_in[2];
    const float* b1 = (const float*)d_in[3];
    const float* W2 = (const float*)d_in[4];
    const float* b2 = (const float*)d_in[5];
    const float* g1 = (const float*)d_in[6];
    const float* be1 = (const float*)d_in[7];
    const float* g2 = (const float*)d_in[8];
    const float* be2 = (const float*)d_in[9];
    float* out = (float*)d_out;

    const int E = in_sizes[1] / 2;
    const int* erow = ei;
    const int* ecol = ei + E;

    // ---- workspace layout
    ushort* bufA    = (ushort*)d_ws;                         // 6.4M bf16 (h), 12.8MB
    float* dinv     = (float*)d_ws + (size_t)NODES * FOUT;   // 50,000 f (offset 25.6MB)
    int*   deg      = (int*)(dinv + NODES);                  // 50,000 i  } zero region
    int*   cursor   = deg + NODES;                           // 50,000 i  } (reused as Bt)
    float* scaleA   = (float*)(cursor + NODES);              // 128 (old colsum slots)
    float* shiftA   = scaleA + 128;                          // 128
    float* scaleB   = shiftA + 128;                          // 128
    float* shiftB   = scaleB + 128;                          // 128
    int*   offsets  = (int*)(shiftB + 128);                  // 50,001 i
    int*   srcs     = offsets + (NODES + 1);                 // E i
    int*   partials = srcs + E;                              // 98 i
    int*   partpre  = partials + SCAN_NB;                    // 98 i
    float* ps1      = (float*)(partpre + SCAN_NB);           // AGG_NB*128 f
    float* ps2      = ps1 + AGG_NB * 128;                    // AGG_NB*128 f
    // Bt aliases cursor region (dead after fill; wcvt runs after fill)
    ushort* Bt1 = (ushort*)cursor;                           // 128*256 bf16
    ushort* Bt2 = Bt1 + 128 * FIN;                           // 128*128 bf16

    size_t zero_bytes = (size_t)(2 * NODES) * sizeof(int);   // deg + cursor
    hipMemsetAsync(deg, 0, zero_bytes, stream);

    int egrid = (E + 255) / 256;
    deg_kernel<<<egrid, 256, 0, stream>>>(ecol, E, deg);
    scan1_kernel<<<SCAN_NB, 256, 0, stream>>>(deg, partials, NODES);
    scan2_kernel<<<1, 128, 0, stream>>>(partials, partpre, &offsets[NODES], E);
    scan3_kernel<<<SCAN_NB, 256, 0, stream>>>(deg, partpre, offsets, dinv, NODES);
    fill_kernel<<<egrid, 256, 0, stream>>>(erow, ecol, E, offsets, cursor, srcs);
    wcvt_kernel<FIN><<<(128 * FIN) / 256, 256, 0, stream>>>(W1, Bt1);
    wcvt_kernel<FOUT><<<(128 * FOUT) / 256, 256, 0, stream>>>(W2, Bt2);

    const int mg = (NODES + 127) / 128;                 // 391 GEMM blocks
    const int eg = ((size_t)NODES * FOUT + 255) / 256;  // 25000 elementwise blocks

    // ---- layer 1
    gemm_mfma_kernel<FIN, false><<<mg, 256, 0, stream>>>(x, Bt1, b1, nullptr, nullptr, bufA, NODES);
    agg_kernel<<<AGG_NB, 256, 0, stream>>>(bufA, dinv, offsets, srcs, out, ps1, ps2, NODES);
    bn_reduce_kernel<<<1, 1024, 0, stream>>>(ps1, ps2, g1, be1, scaleA, shiftA);

    // ---- layer 2 (BN1+LeakyReLU fused into A-staging)
    gemm_mfma_kernel<FOUT, true><<<mg, 256, 0, stream>>>(out, Bt2, b2, scaleA, shiftA, bufA, NODES);
    agg_kernel<<<AGG_NB, 256, 0, stream>>>(bufA, dinv, offsets, srcs, out, ps1, ps2, NODES);
    bn_reduce_kernel<<<1, 1024, 0, stream>>>(ps1, ps2, g2, be2, scaleB, shiftB);
    bn_apply_kernel<<<eg, 256, 0, stream>>>(out, scaleB, shiftB, NODES);
}

// Round 13
// 303.773 us; speedup vs baseline: 1.4410x; 1.4410x over previous
//
#include <hip/hip_runtime.h>

#define NODES 50000
#define FIN   256
#define FOUT  128
#define EPS   1e-5f
#define SLOPE 0.1f
#define SCAN_CHUNK 512
#define SCAN_NB ((NODES + SCAN_CHUNK - 1) / SCAN_CHUNK)  // 98
#define AGG_NB 2048

typedef __attribute__((ext_vector_type(8))) short short8_t;   // 8 bf16 = 4 VGPRs
typedef __attribute__((ext_vector_type(4))) float f32x4_t;    // MFMA accumulator

// fp32 -> bf16 bits, round-to-nearest-even
__device__ __forceinline__ ushort f2bf(float f) {
    union { float f; unsigned u; } v; v.f = f;
    return (ushort)((v.u + 0x7FFFu + ((v.u >> 16) & 1u)) >> 16);
}
// bf16 bits -> fp32
__device__ __forceinline__ float bf2f(ushort u) {
    union { unsigned x; float f; } v; v.x = ((unsigned)u) << 16; return v.f;
}

// ---------------------------------------------------------------- degree count
__global__ void deg_kernel(const int* __restrict__ col, int E, int* __restrict__ deg) {
    int e = blockIdx.x * 256 + threadIdx.x;
    if (e < E) atomicAdd(&deg[col[e]], 1);
}

// ------------------------------------------------- hierarchical scan, pass 1
__global__ __launch_bounds__(256) void scan1_kernel(const int* __restrict__ deg,
                                                    int* __restrict__ partials, int Nn) {
    const int t = threadIdx.x;
    const int i0 = blockIdx.x * SCAN_CHUNK + 2 * t;
    int e0 = (i0 < Nn) ? deg[i0] : 0;
    int e1 = (i0 + 1 < Nn) ? deg[i0 + 1] : 0;
    __shared__ int sh[256];
    sh[t] = e0 + e1;
    __syncthreads();
    for (int off = 128; off > 0; off >>= 1) {
        if (t < off) sh[t] += sh[t + off];
        __syncthreads();
    }
    if (t == 0) partials[blockIdx.x] = sh[0];
}

// ------------------------------------------------- pass 2: scan partials
__global__ __launch_bounds__(128) void scan2_kernel(const int* __restrict__ partials,
                                                    int* __restrict__ partials_pre,
                                                    int* __restrict__ offN, int total) {
    __shared__ int sh[128];
    const int t = threadIdx.x;
    int v = (t < SCAN_NB) ? partials[t] : 0;
    sh[t] = v;
    __syncthreads();
    for (int off = 1; off < 128; off <<= 1) {
        int u = (t >= off) ? sh[t - off] : 0;
        __syncthreads();
        sh[t] += u;
        __syncthreads();
    }
    if (t < SCAN_NB) partials_pre[t] = sh[t] - v;
    if (t == 0) *offN = total;
}

// ------------------------------------------------- pass 3: in-block scan + prefix (+ fused dinv)
__global__ __launch_bounds__(256) void scan3_kernel(const int* __restrict__ deg,
                                                    const int* __restrict__ partials_pre,
                                                    int* __restrict__ offsets,
                                                    float* __restrict__ dinv, int Nn) {
    const int t = threadIdx.x;
    const int i0 = blockIdx.x * SCAN_CHUNK + 2 * t;
    int e0 = (i0 < Nn) ? deg[i0] : 0;
    int e1 = (i0 + 1 < Nn) ? deg[i0 + 1] : 0;
    int s = e0 + e1;
    __shared__ int sh[256];
    sh[t] = s;
    __syncthreads();
    for (int off = 1; off < 256; off <<= 1) {
        int u = (t >= off) ? sh[t - off] : 0;
        __syncthreads();
        sh[t] += u;
        __syncthreads();
    }
    int ex = sh[t] - s + partials_pre[blockIdx.x];
    if (i0 < Nn)     { offsets[i0] = ex;          dinv[i0] = rsqrtf((float)(e0 + 1)); }
    if (i0 + 1 < Nn) { offsets[i0 + 1] = ex + e0; dinv[i0 + 1] = rsqrtf((float)(e1 + 1)); }
}

// ---------------------------------------------------------------- CSR fill
__global__ void fill_kernel(const int* __restrict__ row, const int* __restrict__ col, int E,
                            const int* __restrict__ offsets, int* __restrict__ cursor,
                            int* __restrict__ srcs) {
    int e = blockIdx.x * 256 + threadIdx.x;
    if (e < E) {
        int c = col[e];
        int p = offsets[c] + atomicAdd(&cursor[c], 1);
        srcs[p] = row[e];
    }
}

// ---------------------------------------------------------------- W -> bf16 transposed
template <int K>
__global__ __launch_bounds__(256) void wcvt_kernel(const float* __restrict__ W,
                                                   ushort* __restrict__ Bt) {
    int idx = blockIdx.x * 256 + threadIdx.x;
    int k = idx >> 7, n = idx & 127;
    if (k < K) Bt[n * K + k] = f2bf(W[idx]);
}

// ---------------------------------------------------------------- BN partial reduce -> scale/shift
// ps1/ps2 transposed: [feature][AGG_NB]. One block per feature, coalesced.
__global__ __launch_bounds__(256) void bn_reduce_kernel(const float* __restrict__ ps1,
                                                        const float* __restrict__ ps2,
                                                        const float* __restrict__ gamma,
                                                        const float* __restrict__ beta,
                                                        float* __restrict__ scale,
                                                        float* __restrict__ shift) {
    const int f = blockIdx.x;
    const int t = threadIdx.x;
    float s1 = 0.f, s2 = 0.f;
    for (int b = t; b < AGG_NB; b += 256) {
        s1 += ps1[(size_t)f * AGG_NB + b];
        s2 += ps2[(size_t)f * AGG_NB + b];
    }
    __shared__ float r1[256], r2[256];
    r1[t] = s1;
    r2[t] = s2;
    __syncthreads();
    for (int off = 128; off > 0; off >>= 1) {
        if (t < off) { r1[t] += r1[t + off]; r2[t] += r2[t + off]; }
        __syncthreads();
    }
    if (t == 0) {
        const float invN = 1.0f / (float)NODES;
        float mu  = r1[0] * invN;
        float var = r2[0] * invN - mu * mu;
        float sc  = gamma[f] * rsqrtf(var + EPS);
        scale[f] = sc;
        shift[f] = beta[f] - mu * sc;
    }
}

// ---------------------------------------------------------------- bf16 MFMA GEMM + bias (+opt fused BN+LeakyReLU on A)
// C[M,128] (bf16) = act(A[M,K]) @ B[K,128] + bias, act = FUSE ? leakyrelu(A*scale+shift) : A.
// Bt = B^T bf16 [128][K]. BM=128, BN=128, BK=32; 4 waves x (2 m-tiles x 8 n-tiles) 16x16x32.
// Fragment mapping (HW-verified, guide §3 m89/m91):
//   A: lane l -> A[l&15][(l>>4)*8+j] ; B: lane l -> B[(l>>4)*8+j][l&15]
//   D: lane l, reg r -> C[(l>>4)*4+r][l&15]
template <int K, bool FUSE>
__global__ __launch_bounds__(256) void gemm_mfma_kernel(const float* __restrict__ A,
                                                        const ushort* __restrict__ Bt,
                                                        const float* __restrict__ bias,
                                                        const float* __restrict__ scale,
                                                        const float* __restrict__ shift,
                                                        ushort* __restrict__ C, int M) {
    __shared__ ushort As[128 * 40];  // [row][k] bf16, row stride 40 (pad)
    __shared__ ushort Bs[128 * 40];  // [n][k]   bf16, row stride 40 (pad)
    const int tid  = threadIdx.x;
    const int lane = tid & 63;
    const int w    = tid >> 6;
    const int m0   = blockIdx.x * 128;
    const int ml   = lane & 15;
    const int kg   = lane >> 4;

    f32x4_t acc[2][8];
    const f32x4_t zero = {0.f, 0.f, 0.f, 0.f};
#pragma unroll
    for (int a = 0; a < 2; ++a)
#pragma unroll
        for (int b = 0; b < 8; ++b) acc[a][b] = zero;

    const int sr = tid >> 1;
    const int sh = tid & 1;
    const bool aok = (m0 + sr) < M;
    const float* ap = A + (size_t)(m0 + sr) * K + sh * 16;

    for (int k0 = 0; k0 < K; k0 += 32) {
        __syncthreads();
        // ---- stage A tile [128][32] fp32 -> (BN+lrelu) -> bf16
        float vv[16];
        if (aok) {
            const float* p = ap + k0;
            *(float4*)&vv[0]  = *(const float4*)(p + 0);
            *(float4*)&vv[4]  = *(const float4*)(p + 4);
            *(float4*)&vv[8]  = *(const float4*)(p + 8);
            *(float4*)&vv[12] = *(const float4*)(p + 12);
            if (FUSE) {
                int kb = k0 + sh * 16;
#pragma unroll
                for (int j = 0; j < 16; ++j) {
                    float val = fmaf(vv[j], scale[kb + j], shift[kb + j]);
                    vv[j] = (val >= 0.f) ? val : SLOPE * val;
                }
            }
        } else {
#pragma unroll
            for (int j = 0; j < 16; ++j) vv[j] = 0.f;
        }
        short8_t oa, ob;
#pragma unroll
        for (int j = 0; j < 8; ++j) { oa[j] = (short)f2bf(vv[j]); ob[j] = (short)f2bf(vv[8 + j]); }
        *(short8_t*)&As[sr * 40 + sh * 16]     = oa;
        *(short8_t*)&As[sr * 40 + sh * 16 + 8] = ob;
        // ---- stage B tile [128][32]
#pragma unroll
        for (int cc = 0; cc < 2; ++cc) {
            int c  = tid + cc * 256;
            int bn = c >> 2;
            int bs = (c & 3) * 8;
            *(short8_t*)&Bs[bn * 40 + bs] = *(const short8_t*)&Bt[bn * K + k0 + bs];
        }
        __syncthreads();
        // ---- 16 MFMA
        short8_t af0 = *(const short8_t*)&As[(w * 32 + ml) * 40 + kg * 8];
        short8_t af1 = *(const short8_t*)&As[(w * 32 + 16 + ml) * 40 + kg * 8];
#pragma unroll
        for (int nt = 0; nt < 8; ++nt) {
            short8_t bf = *(const short8_t*)&Bs[(nt * 16 + ml) * 40 + kg * 8];
            acc[0][nt] = __builtin_amdgcn_mfma_f32_16x16x32_bf16(af0, bf, acc[0][nt], 0, 0, 0);
            acc[1][nt] = __builtin_amdgcn_mfma_f32_16x16x32_bf16(af1, bf, acc[1][nt], 0, 0, 0);
        }
    }
    // ---- epilogue: bias + store bf16
#pragma unroll
    for (int nt = 0; nt < 8; ++nt) {
        float bv = bias[nt * 16 + ml];
#pragma unroll
        for (int mt = 0; mt < 2; ++mt) {
            int mr0 = m0 + w * 32 + mt * 16 + kg * 4;
#pragma unroll
            for (int rr = 0; rr < 4; ++rr) {
                int mr = mr0 + rr;
                if (mr < M) C[(size_t)mr * FOUT + nt * 16 + ml] = f2bf(acc[mt][nt][rr] + bv);
            }
        }
    }
}

// ---------------------------------------------------------------- aggregation + fused BN stats
// out[i] = dinv[i]^2 * h[i] + sum_{s in N(i)} dinv[i]*dinv[s]*h[s]  (h bf16, out fp32)
// One node per 16-lane group (16 x ushort8 = 128 bf16 = 256B/row), 16 nodes/block,
// grid-stride over nodes. Per-thread register accumulation of per-feature
// sum/sumsq, block LDS reduce, TRANSPOSED partial write ps[f][block].
__global__ __launch_bounds__(256) void agg_kernel(const ushort* __restrict__ h,
                                                  const float* __restrict__ dinv,
                                                  const int* __restrict__ offsets,
                                                  const int* __restrict__ srcs,
                                                  float* __restrict__ out,
                                                  float* __restrict__ ps1,
                                                  float* __restrict__ ps2, int Nn) {
    const int tid  = threadIdx.x;
    const int g    = tid >> 4;   // 0..15 group
    const int lane = tid & 15;   // 0..15
    float s1[8], s2[8];
#pragma unroll
    for (int j = 0; j < 8; ++j) { s1[j] = 0.f; s2[j] = 0.f; }

    for (int node = blockIdx.x * 16 + g; node < Nn; node += AGG_NB * 16) {
        float di = dinv[node];
        short8_t hv = *(const short8_t*)&h[(size_t)node * 128 + lane * 8];
        float sw = di * di;
        float a0[8], a1[8];
#pragma unroll
        for (int j = 0; j < 8; ++j) { a0[j] = sw * bf2f((ushort)hv[j]); a1[j] = 0.f; }
        int beg = offsets[node], end = offsets[node + 1];
        int e = beg;
        for (; e + 4 <= end; e += 4) {
            int i0 = srcs[e], i1 = srcs[e + 1], i2 = srcs[e + 2], i3 = srcs[e + 3];
            float n0 = di * dinv[i0], n1 = di * dinv[i1];
            float n2 = di * dinv[i2], n3 = di * dinv[i3];
            short8_t v0 = *(const short8_t*)&h[(size_t)i0 * 128 + lane * 8];
            short8_t v1 = *(const short8_t*)&h[(size_t)i1 * 128 + lane * 8];
            short8_t v2 = *(const short8_t*)&h[(size_t)i2 * 128 + lane * 8];
            short8_t v3 = *(const short8_t*)&h[(size_t)i3 * 128 + lane * 8];
#pragma unroll
            for (int j = 0; j < 8; ++j) {
                a0[j] = fmaf(n0, bf2f((ushort)v0[j]), a0[j]);
                a1[j] = fmaf(n1, bf2f((ushort)v1[j]), a1[j]);
                a0[j] = fmaf(n2, bf2f((ushort)v2[j]), a0[j]);
                a1[j] = fmaf(n3, bf2f((ushort)v3[j]), a1[j]);
            }
        }
        for (; e < end; ++e) {
            int s = srcs[e];
            float n = di * dinv[s];
            short8_t v = *(const short8_t*)&h[(size_t)s * 128 + lane * 8];
#pragma unroll
            for (int j = 0; j < 8; ++j) a0[j] = fmaf(n, bf2f((ushort)v[j]), a0[j]);
        }
        float4 o0, o1;
        o0.x = a0[0] + a1[0]; o0.y = a0[1] + a1[1];
        o0.z = a0[2] + a1[2]; o0.w = a0[3] + a1[3];
        o1.x = a0[4] + a1[4]; o1.y = a0[5] + a1[5];
        o1.z = a0[6] + a1[6]; o1.w = a0[7] + a1[7];
        float* op = &out[(size_t)node * 128 + lane * 8];
        *(float4*)op       = o0;
        *(float4*)(op + 4) = o1;
        s1[0] += o0.x; s2[0] += o0.x * o0.x;  s1[1] += o0.y; s2[1] += o0.y * o0.y;
        s1[2] += o0.z; s2[2] += o0.z * o0.z;  s1[3] += o0.w; s2[3] += o0.w * o0.w;
        s1[4] += o1.x; s2[4] += o1.x * o1.x;  s1[5] += o1.y; s2[5] += o1.y * o1.y;
        s1[6] += o1.z; s2[6] += o1.z * o1.z;  s1[7] += o1.w; s2[7] += o1.w * o1.w;
    }

    // block reduce: feature f = lane*8 + j; sum over the 16 groups.
    // write TRANSPOSED: ps[f * AGG_NB + block] (1MB L2-resident buffer)
    __shared__ float red[256][8];
#pragma unroll
    for (int j = 0; j < 8; ++j) red[tid][j] = s1[j];
    __syncthreads();
    if (tid < 128) {
        int ln = tid >> 3, jj = tid & 7;
        float s = 0.f;
#pragma unroll
        for (int gg = 0; gg < 16; ++gg) s += red[gg * 16 + ln][jj];
        ps1[(size_t)tid * AGG_NB + blockIdx.x] = s;
    }
    __syncthreads();
#pragma unroll
    for (int j = 0; j < 8; ++j) red[tid][j] = s2[j];
    __syncthreads();
    if (tid < 128) {
        int ln = tid >> 3, jj = tid & 7;
        float s = 0.f;
#pragma unroll
        for (int gg = 0; gg < 16; ++gg) s += red[gg * 16 + ln][jj];
        ps2[(size_t)tid * AGG_NB + blockIdx.x] = s;
    }
}

// ---------------------------------------------------------------- BN apply (scale/shift) + leaky relu
__global__ __launch_bounds__(256) void bn_apply_kernel(float* __restrict__ x,
                                                       const float* __restrict__ scale,
                                                       const float* __restrict__ shift, int Nn) {
    size_t i = (size_t)blockIdx.x * 256 + threadIdx.x;
    if (i >= (size_t)Nn * FOUT) return;
    int f = (int)(i & 127);
    float v = fmaf(x[i], scale[f], shift[f]);
    x[i] = (v >= 0.f) ? v : SLOPE * v;
}

// ================================================================ launch
extern "C" void kernel_launch(void* const* d_in, const int* in_sizes, int n_in,
                              void* d_out, int out_size, void* d_ws, size_t ws_size,
                              hipStream_t stream) {
    const float* x  = (const float*)d_in[0];
    const int*   ei = (const int*)d_in[1];
    const float* W1 = (const float*)d_in[2];
    const float* b1 = (const float*)d_in[3];
    const float* W2 = (const float*)d_in[4];
    const float* b2 = (const float*)d_in[5];
    const float* g1 = (const float*)d_in[6];
    const float* be1 = (const float*)d_in[7];
    const float* g2 = (const float*)d_in[8];
    const float* be2 = (const float*)d_in[9];
    float* out = (float*)d_out;

    const int E = in_sizes[1] / 2;
    const int* erow = ei;
    const int* ecol = ei + E;

    // ---- workspace layout
    ushort* bufA    = (ushort*)d_ws;                         // 6.4M bf16 (h), 12.8MB
    float* dinv     = (float*)d_ws + (size_t)NODES * FOUT;   // 50,000 f (offset 25.6MB)
    int*   deg      = (int*)(dinv + NODES);                  // 50,000 i  } zero region
    int*   cursor   = deg + NODES;                           // 50,000 i  } (reused as Bt)
    float* scaleA   = (float*)(cursor + NODES);              // 128
    float* shiftA   = scaleA + 128;                          // 128
    float* scaleB   = shiftA + 128;                          // 128
    float* shiftB   = scaleB + 128;                          // 128
    int*   offsets  = (int*)(shiftB + 128);                  // 50,001 i
    int*   srcs     = offsets + (NODES + 1);                 // E i
    int*   partials = srcs + E;                              // 98 i
    int*   partpre  = partials + SCAN_NB;                    // 98 i
    float* ps1      = (float*)(partpre + SCAN_NB);           // 128*AGG_NB f (transposed)
    float* ps2      = ps1 + 128 * AGG_NB;                    // 128*AGG_NB f
    // Bt aliases cursor region (dead after fill; wcvt runs after fill)
    ushort* Bt1 = (ushort*)cursor;                           // 128*256 bf16
    ushort* Bt2 = Bt1 + 128 * FIN;                           // 128*128 bf16

    size_t zero_bytes = (size_t)(2 * NODES) * sizeof(int);   // deg + cursor
    hipMemsetAsync(deg, 0, zero_bytes, stream);

    int egrid = (E + 255) / 256;
    deg_kernel<<<egrid, 256, 0, stream>>>(ecol, E, deg);
    scan1_kernel<<<SCAN_NB, 256, 0, stream>>>(deg, partials, NODES);
    scan2_kernel<<<1, 128, 0, stream>>>(partials, partpre, &offsets[NODES], E);
    scan3_kernel<<<SCAN_NB, 256, 0, stream>>>(deg, partpre, offsets, dinv, NODES);
    fill_kernel<<<egrid, 256, 0, stream>>>(erow, ecol, E, offsets, cursor, srcs);
    wcvt_kernel<FIN><<<(128 * FIN) / 256, 256, 0, stream>>>(W1, Bt1);
    wcvt_kernel<FOUT><<<(128 * FOUT) / 256, 256, 0, stream>>>(W2, Bt2);

    const int mg = (NODES + 127) / 128;                 // 391 GEMM blocks
    const int eg = ((size_t)NODES * FOUT + 255) / 256;  // 25000 elementwise blocks

    // ---- layer 1
    gemm_mfma_kernel<FIN, false><<<mg, 256, 0, stream>>>(x, Bt1, b1, nullptr, nullptr, bufA, NODES);
    agg_kernel<<<AGG_NB, 256, 0, stream>>>(bufA, dinv, offsets, srcs, out, ps1, ps2, NODES);
    bn_reduce_kernel<<<128, 256, 0, stream>>>(ps1, ps2, g1, be1, scaleA, shiftA);

    // ---- layer 2 (BN1+LeakyReLU fused into A-staging)
    gemm_mfma_kernel<FOUT, true><<<mg, 256, 0, stream>>>(out, Bt2, b2, scaleA, shiftA, bufA, NODES);
    agg_kernel<<<AGG_NB, 256, 0, stream>>>(bufA, dinv, offsets, srcs, out, ps1, ps2, NODES);
    bn_reduce_kernel<<<128, 256, 0, stream>>>(ps1, ps2, g2, be2, scaleB, shiftB);
    bn_apply_kernel<<<eg, 256, 0, stream>>>(out, scaleB, shiftB, NODES);
}